// Round 1
// baseline (916.666 us; speedup 1.0000x reference)
//
#include <hip/hip_runtime.h>
#include <hip/hip_bf16.h>
#include <float.h>
#include <math.h>

// MultiScaleReadout: mean/max/attention/local-MLP segment pooling.
// N=500000 nodes, D=256, G=1024 segments (batch sorted), H=L=128.
// Structure:
//   k_prep       : bf16-transpose w1/lp_w -> [128][256], zero local_sum
//   k_gate_local : MFMA bf16 matmuls -> gate[N] (global) + per-segment local sums (atomics)
//   k_pool       : one block per segment; softmax stats over gate; one coalesced
//                  float4 pass over x accumulating mean/max/att; write out [G,896]

typedef __bf16 bf16;
typedef __bf16 bf16x8 __attribute__((ext_vector_type(8)));
typedef float f32x4 __attribute__((ext_vector_type(4)));

#define D 256
#define HDIM 128
#define LDIM 128
#define EBUF 768

__device__ __forceinline__ float gelu_f(float v) {
    return 0.5f * v * (1.0f + erff(v * 0.70710678118654752f));
}

// ---------------- Kernel 0: prep ----------------
__global__ __launch_bounds__(256) void k_prep(const float* __restrict__ w1,
                                              const float* __restrict__ lpw,
                                              bf16* __restrict__ w1T,
                                              bf16* __restrict__ lpT,
                                              float* __restrict__ local_sum,
                                              int G) {
    int t = blockIdx.x * 256 + threadIdx.x;
    if (t < G * LDIM) local_sum[t] = 0.0f;
    if (t < HDIM * D) {
        int n = t >> 8;   // output col (n)
        int k = t & 255;  // k index
        w1T[t] = (bf16)w1[k * HDIM + n];
        lpT[t] = (bf16)lpw[k * LDIM + n];
    }
}

// ---------------- Kernel 1: gate + local segment sums ----------------
// block = 256 threads (4 waves), tile = 64 nodes.
// wave w owns output cols [32w, 32w+32) as two 16-wide n-tiles.
__global__ __launch_bounds__(256) void k_gate_local(
    const float* __restrict__ x, const int* __restrict__ batch,
    const bf16* __restrict__ w1T, const float* __restrict__ b1,
    const float* __restrict__ w2, const float* __restrict__ b2,
    const bf16* __restrict__ lpT, const float* __restrict__ lpb,
    float* __restrict__ gate, float* __restrict__ local_sum, int N)
{
    __shared__ bf16 xs[64][264];   // +8 bf16 pad -> b128 reads are 2-way-only aliasing
    __shared__ int bs[64];
    __shared__ float gpart[4][64];

    const int tid  = threadIdx.x;
    const int wave = tid >> 6;
    const int lane = tid & 63;
    const int quad = lane >> 4;
    const int l16  = lane & 15;
    const long base = (long)blockIdx.x * 64;

    // stage x tile -> bf16 LDS (coalesced float4 reads, one row per wave per iter)
    #pragma unroll
    for (int it = 0; it < 16; ++it) {
        int idx = it * 256 + tid;
        int row = idx >> 6;
        int c4  = idx & 63;
        long node = base + row;
        float4 v;
        if (node < N) v = *(const float4*)(x + node * D + c4 * 4);
        else          v = make_float4(0.f, 0.f, 0.f, 0.f);
        bf16* dst = &xs[row][c4 * 4];
        dst[0] = (bf16)v.x; dst[1] = (bf16)v.y; dst[2] = (bf16)v.z; dst[3] = (bf16)v.w;
    }
    if (tid < 64) bs[tid] = (base + tid < N) ? batch[base + tid] : 0x7fffffff;
    __syncthreads();

    const int c0 = wave * 32 + l16;
    const int c1 = c0 + 16;

    f32x4 zero = {0.f, 0.f, 0.f, 0.f};

    // ---- matmul 1: h = x @ w1 ----
    f32x4 acc0[4], acc1[4];
    #pragma unroll
    for (int mt = 0; mt < 4; ++mt) { acc0[mt] = zero; acc1[mt] = zero; }
    #pragma unroll
    for (int kt = 0; kt < 8; ++kt) {
        int k0 = kt * 32 + quad * 8;
        bf16x8 bfr0 = *(const bf16x8*)(w1T + c0 * D + k0);
        bf16x8 bfr1 = *(const bf16x8*)(w1T + c1 * D + k0);
        #pragma unroll
        for (int mt = 0; mt < 4; ++mt) {
            bf16x8 a = *(const bf16x8*)(&xs[mt * 16 + l16][k0]);
            acc0[mt] = __builtin_amdgcn_mfma_f32_16x16x32_bf16(a, bfr0, acc0[mt], 0, 0, 0);
            acc1[mt] = __builtin_amdgcn_mfma_f32_16x16x32_bf16(a, bfr1, acc1[mt], 0, 0, 0);
        }
    }

    // gate row-partials: gelu(h + b1) * w2, reduce over 128 cols
    {
        const float b1c0 = b1[c0], b1c1 = b1[c1];
        const float w2c0 = w2[c0], w2c1 = w2[c1];
        #pragma unroll
        for (int mt = 0; mt < 4; ++mt) {
            #pragma unroll
            for (int r = 0; r < 4; ++r) {
                float v = gelu_f(acc0[mt][r] + b1c0) * w2c0
                        + gelu_f(acc1[mt][r] + b1c1) * w2c1;
                v += __shfl_down(v, 8, 16);
                v += __shfl_down(v, 4, 16);
                v += __shfl_down(v, 2, 16);
                v += __shfl_down(v, 1, 16);
                if (l16 == 0) gpart[wave][mt * 16 + quad * 4 + r] = v;
            }
        }
    }
    __syncthreads();
    if (tid < 64) {
        long node = base + tid;
        if (node < N)
            gate[node] = gpart[0][tid] + gpart[1][tid] + gpart[2][tid] + gpart[3][tid] + b2[0];
    }

    // ---- matmul 2: local = x @ lp_w ----
    #pragma unroll
    for (int mt = 0; mt < 4; ++mt) { acc0[mt] = zero; acc1[mt] = zero; }
    #pragma unroll
    for (int kt = 0; kt < 8; ++kt) {
        int k0 = kt * 32 + quad * 8;
        bf16x8 bfr0 = *(const bf16x8*)(lpT + c0 * D + k0);
        bf16x8 bfr1 = *(const bf16x8*)(lpT + c1 * D + k0);
        #pragma unroll
        for (int mt = 0; mt < 4; ++mt) {
            bf16x8 a = *(const bf16x8*)(&xs[mt * 16 + l16][k0]);
            acc0[mt] = __builtin_amdgcn_mfma_f32_16x16x32_bf16(a, bfr0, acc0[mt], 0, 0, 0);
            acc1[mt] = __builtin_amdgcn_mfma_f32_16x16x32_bf16(a, bfr1, acc1[mt], 0, 0, 0);
        }
    }

    const float lb0 = lpb[c0], lb1 = lpb[c1];
    const bool fast = (base + 63 < N) && (bs[0] == bs[63]);
    if (fast) {
        // whole tile in one segment: block-wide column sums, one atomic per col
        float s0 = 0.f, s1 = 0.f;
        #pragma unroll
        for (int mt = 0; mt < 4; ++mt) {
            #pragma unroll
            for (int r = 0; r < 4; ++r) {
                s0 += gelu_f(acc0[mt][r] + lb0);
                s1 += gelu_f(acc1[mt][r] + lb1);
            }
        }
        s0 += __shfl_xor(s0, 16); s0 += __shfl_xor(s0, 32);
        s1 += __shfl_xor(s1, 16); s1 += __shfl_xor(s1, 32);
        if (quad == 0) {
            int g = bs[0];
            atomicAdd(&local_sum[g * LDIM + c0], s0);
            atomicAdd(&local_sum[g * LDIM + c1], s1);
        }
    } else {
        // boundary tile: per-lane running flush in increasing-node order
        int cur = -1;
        float s0 = 0.f, s1 = 0.f;
        #pragma unroll
        for (int mt = 0; mt < 4; ++mt) {
            #pragma unroll
            for (int r = 0; r < 4; ++r) {
                int lrow = mt * 16 + quad * 4 + r;
                if (base + lrow < N) {
                    int g = bs[lrow];
                    if (g != cur) {
                        if (cur >= 0) {
                            atomicAdd(&local_sum[cur * LDIM + c0], s0);
                            atomicAdd(&local_sum[cur * LDIM + c1], s1);
                        }
                        cur = g; s0 = 0.f; s1 = 0.f;
                    }
                    s0 += gelu_f(acc0[mt][r] + lb0);
                    s1 += gelu_f(acc1[mt][r] + lb1);
                }
            }
        }
        if (cur >= 0) {
            atomicAdd(&local_sum[cur * LDIM + c0], s0);
            atomicAdd(&local_sum[cur * LDIM + c1], s1);
        }
    }
}

// ---------------- Kernel 2: per-segment pooling ----------------
__device__ __forceinline__ int lower_bound_i(const int* a, int n, int v) {
    int lo = 0, hi = n;
    while (lo < hi) { int mid = (lo + hi) >> 1; if (a[mid] < v) lo = mid + 1; else hi = mid; }
    return lo;
}

__global__ __launch_bounds__(256) void k_pool(
    const float* __restrict__ x, const int* __restrict__ batch,
    const float* __restrict__ gate, const float* __restrict__ local_sum,
    float* __restrict__ out, int N)
{
    const int g   = blockIdx.x;
    const int tid = threadIdx.x;
    const int wave = tid >> 6;
    const int lane = tid & 63;

    __shared__ int sse[2];
    __shared__ float wred[4];
    __shared__ float ebuf[EBUF];
    __shared__ float rsum[4][256];
    __shared__ float rmax[4][256];
    __shared__ float ratt[4][256];

    if (tid == 0) {
        sse[0] = lower_bound_i(batch, N, g);
        sse[1] = lower_bound_i(batch, N, g + 1);
    }
    __syncthreads();
    const int start = sse[0], end = sse[1];
    const int cnt = end - start;

    // segment max of gate
    float m = -FLT_MAX;
    for (int i = start + tid; i < end; i += 256) m = fmaxf(m, gate[i]);
    #pragma unroll
    for (int off = 32; off > 0; off >>= 1) m = fmaxf(m, __shfl_xor(m, off));
    if (lane == 0) wred[wave] = m;
    __syncthreads();
    m = fmaxf(fmaxf(wred[0], wred[1]), fmaxf(wred[2], wred[3]));
    __syncthreads();

    // denom + exp cache
    const bool fits = (cnt <= EBUF);
    float dsum = 0.f;
    for (int i = start + tid; i < end; i += 256) {
        float e = expf(gate[i] - m);
        if (fits) ebuf[i - start] = e;
        dsum += e;
    }
    #pragma unroll
    for (int off = 32; off > 0; off >>= 1) dsum += __shfl_xor(dsum, off);
    __syncthreads();
    if (lane == 0) wred[wave] = dsum;
    __syncthreads();
    const float denom = wred[0] + wred[1] + wred[2] + wred[3];

    // main pass over x: 4 row-groups x 64 float4-cols
    const int rg = tid >> 6;
    const int c4 = tid & 63;
    float sx = 0, sy = 0, sz = 0, sw = 0;
    float ax = 0, ay = 0, az = 0, aw = 0;
    float mx = -FLT_MAX, my = -FLT_MAX, mz = -FLT_MAX, mw = -FLT_MAX;
    for (int r0 = start; r0 < end; r0 += 4) {
        int r = r0 + rg;
        if (r < end) {
            float e = fits ? ebuf[r - start] : expf(gate[r] - m);
            float4 v = *(const float4*)(x + (long)r * D + c4 * 4);
            sx += v.x; sy += v.y; sz += v.z; sw += v.w;
            ax += e * v.x; ay += e * v.y; az += e * v.z; aw += e * v.w;
            mx = fmaxf(mx, v.x); my = fmaxf(my, v.y); mz = fmaxf(mz, v.z); mw = fmaxf(mw, v.w);
        }
    }
    const int cb = c4 * 4;
    rsum[rg][cb] = sx; rsum[rg][cb+1] = sy; rsum[rg][cb+2] = sz; rsum[rg][cb+3] = sw;
    ratt[rg][cb] = ax; ratt[rg][cb+1] = ay; ratt[rg][cb+2] = az; ratt[rg][cb+3] = aw;
    rmax[rg][cb] = mx; rmax[rg][cb+1] = my; rmax[rg][cb+2] = mz; rmax[rg][cb+3] = mw;
    __syncthreads();

    const float cntf = fmaxf((float)cnt, 1.0f);
    const float inv  = 1.0f / cntf;
    const float invd = (denom > 0.f) ? 1.0f / denom : 0.f;
    const long o = (long)g * 896;

    {   // col = tid (0..255)
        int c = tid;
        float s  = rsum[0][c] + rsum[1][c] + rsum[2][c] + rsum[3][c];
        float a  = ratt[0][c] + ratt[1][c] + ratt[2][c] + ratt[3][c];
        float mm = fmaxf(fmaxf(rmax[0][c], rmax[1][c]), fmaxf(rmax[2][c], rmax[3][c]));
        if (cnt == 0) mm = -INFINITY;   // match jax segment_max identity
        out[o + c]       = s * inv;
        out[o + 256 + c] = mm;
        out[o + 512 + c] = a * invd;
    }
    if (tid < 128) out[o + 768 + tid] = local_sum[g * LDIM + tid] * inv;
}

// ---------------- launch ----------------
extern "C" void kernel_launch(void* const* d_in, const int* in_sizes, int n_in,
                              void* d_out, int out_size, void* d_ws, size_t ws_size,
                              hipStream_t stream) {
    const float* x   = (const float*)d_in[0];
    const int* batch = (const int*)d_in[1];
    const float* w1  = (const float*)d_in[2];
    const float* b1  = (const float*)d_in[3];
    const float* w2  = (const float*)d_in[4];
    const float* b2  = (const float*)d_in[5];
    const float* lpw = (const float*)d_in[6];
    const float* lpb = (const float*)d_in[7];
    float* out = (float*)d_out;

    const int N = in_sizes[0] / D;
    const int G = out_size / 896;

    char* ws = (char*)d_ws;
    size_t off = 0;
    float* gate = (float*)(ws + off); off += (((size_t)N * 4) + 255) & ~(size_t)255;
    bf16* w1T   = (bf16*)(ws + off);  off += (size_t)HDIM * D * 2;
    bf16* lpT   = (bf16*)(ws + off);  off += (size_t)LDIM * D * 2;
    float* local_sum = (float*)(ws + off); off += (size_t)G * LDIM * 4;

    const int prep_threads = G * LDIM;  // covers both the zeroing and the 32K-elem transposes
    k_prep<<<(prep_threads + 255) / 256, 256, 0, stream>>>(w1, lpw, w1T, lpT, local_sum, G);
    k_gate_local<<<(int)((N + 63) / 64), 256, 0, stream>>>(x, batch, w1T, b1, w2, b2,
                                                           lpT, lpb, gate, local_sum, N);
    k_pool<<<G, 256, 0, stream>>>(x, batch, gate, local_sum, out, N);
}

// Round 2
// 883.181 us; speedup vs baseline: 1.0379x; 1.0379x over previous
//
#include <hip/hip_runtime.h>
#include <hip/hip_bf16.h>
#include <float.h>
#include <math.h>

// MultiScaleReadout: mean/max/attention/local-MLP segment pooling.
// N=500000 nodes, D=256, G=1024 segments (batch sorted), H=L=128.
// R2 structure:
//   k_prep       : bf16-transpose w1/lp_w -> [128][256], zero local_sum, segstart[G]=N
//   k_gate_local : ONE fused MFMA pass (A-frag shared by 4 MFMAs) -> gate[N] + local sums
//   k_stats      : per-segment softmax stats over gate (2 MB) -> aw[i]=e_i, segdenom, segstart
//   k_pool       : 2 blocks/segment (column split), guard-free unrolled stream over x

typedef __bf16 bf16;
typedef __bf16 bf16x4 __attribute__((ext_vector_type(4)));
typedef __bf16 bf16x8 __attribute__((ext_vector_type(8)));
typedef float f32x4 __attribute__((ext_vector_type(4)));

#define D 256
#define HDIM 128
#define LDIM 128

__device__ __forceinline__ float gelu_f(float v) {
    return 0.5f * v * (1.0f + erff(v * 0.70710678118654752f));
}

// ---------------- Kernel 0: prep ----------------
__global__ __launch_bounds__(256) void k_prep(const float* __restrict__ w1,
                                              const float* __restrict__ lpw,
                                              bf16* __restrict__ w1T,
                                              bf16* __restrict__ lpT,
                                              float* __restrict__ local_sum,
                                              int* __restrict__ segstart,
                                              int G, int N) {
    int t = blockIdx.x * 256 + threadIdx.x;
    if (t == 0) segstart[G] = N;
    if (t < G * LDIM) local_sum[t] = 0.0f;
    if (t < HDIM * D) {
        int n = t >> 8;   // output col
        int k = t & 255;  // k index
        w1T[t] = (bf16)w1[k * HDIM + n];
        lpT[t] = (bf16)lpw[k * LDIM + n];
    }
}

// ---------------- Kernel 1: fused gate + local matmuls ----------------
// block = 256 threads (4 waves), tile = 64 nodes.
// wave w owns output cols [32w, 32w+32); each A-fragment feeds 4 MFMAs.
__global__ __launch_bounds__(256, 3) void k_gate_local(
    const float* __restrict__ x, const int* __restrict__ batch,
    const bf16* __restrict__ w1T, const float* __restrict__ b1,
    const float* __restrict__ w2, const float* __restrict__ b2,
    const bf16* __restrict__ lpT, const float* __restrict__ lpb,
    float* __restrict__ gate, float* __restrict__ local_sum, int N)
{
    __shared__ bf16 xs[64][264];   // +8 bf16 pad
    __shared__ int bs[64];
    __shared__ float gpart[4][64];

    const int tid  = threadIdx.x;
    const int wave = tid >> 6;
    const int lane = tid & 63;
    const int quad = lane >> 4;
    const int l16  = lane & 15;
    const long base = (long)blockIdx.x * 64;

    // stage x tile -> bf16 LDS: coalesced float4 loads, packed b64 LDS stores
    #pragma unroll
    for (int it = 0; it < 16; ++it) {
        int idx = it * 256 + tid;
        int row = idx >> 6;
        int c4  = idx & 63;
        long node = base + row;
        float4 v;
        if (node < N) v = *(const float4*)(x + node * D + c4 * 4);
        else          v = make_float4(0.f, 0.f, 0.f, 0.f);
        bf16x4 pk;
        pk[0] = (bf16)v.x; pk[1] = (bf16)v.y; pk[2] = (bf16)v.z; pk[3] = (bf16)v.w;
        *(bf16x4*)(&xs[row][c4 * 4]) = pk;
    }
    if (tid < 64) bs[tid] = (base + tid < N) ? batch[base + tid] : 0x7fffffff;
    __syncthreads();

    const int c0 = wave * 32 + l16;
    const int c1 = c0 + 16;

    f32x4 zero = {0.f, 0.f, 0.f, 0.f};
    f32x4 h0[4], h1[4], l0[4], l1[4];
    #pragma unroll
    for (int mt = 0; mt < 4; ++mt) { h0[mt] = zero; h1[mt] = zero; l0[mt] = zero; l1[mt] = zero; }

    // fused K-loop: one A-fragment load feeds 4 MFMAs
    #pragma unroll
    for (int kt = 0; kt < 8; ++kt) {
        int k0 = kt * 32 + quad * 8;
        bf16x8 bw0 = *(const bf16x8*)(w1T + c0 * D + k0);
        bf16x8 bw1 = *(const bf16x8*)(w1T + c1 * D + k0);
        bf16x8 bp0 = *(const bf16x8*)(lpT + c0 * D + k0);
        bf16x8 bp1 = *(const bf16x8*)(lpT + c1 * D + k0);
        #pragma unroll
        for (int mt = 0; mt < 4; ++mt) {
            bf16x8 a = *(const bf16x8*)(&xs[mt * 16 + l16][k0]);
            h0[mt] = __builtin_amdgcn_mfma_f32_16x16x32_bf16(a, bw0, h0[mt], 0, 0, 0);
            h1[mt] = __builtin_amdgcn_mfma_f32_16x16x32_bf16(a, bw1, h1[mt], 0, 0, 0);
            l0[mt] = __builtin_amdgcn_mfma_f32_16x16x32_bf16(a, bp0, l0[mt], 0, 0, 0);
            l1[mt] = __builtin_amdgcn_mfma_f32_16x16x32_bf16(a, bp1, l1[mt], 0, 0, 0);
        }
    }

    // gate row-partials: gelu(h + b1) * w2, reduce over 128 cols
    {
        const float b1c0 = b1[c0], b1c1 = b1[c1];
        const float w2c0 = w2[c0], w2c1 = w2[c1];
        #pragma unroll
        for (int mt = 0; mt < 4; ++mt) {
            #pragma unroll
            for (int r = 0; r < 4; ++r) {
                float v = gelu_f(h0[mt][r] + b1c0) * w2c0
                        + gelu_f(h1[mt][r] + b1c1) * w2c1;
                v += __shfl_down(v, 8, 16);
                v += __shfl_down(v, 4, 16);
                v += __shfl_down(v, 2, 16);
                v += __shfl_down(v, 1, 16);
                if (l16 == 0) gpart[wave][mt * 16 + quad * 4 + r] = v;
            }
        }
    }
    __syncthreads();
    if (tid < 64) {
        long node = base + tid;
        if (node < N)
            gate[node] = gpart[0][tid] + gpart[1][tid] + gpart[2][tid] + gpart[3][tid] + b2[0];
    }

    // local segment sums
    const float lb0 = lpb[c0], lb1 = lpb[c1];
    const bool fast = (base + 63 < N) && (bs[0] == bs[63]);
    if (fast) {
        float s0 = 0.f, s1 = 0.f;
        #pragma unroll
        for (int mt = 0; mt < 4; ++mt) {
            #pragma unroll
            for (int r = 0; r < 4; ++r) {
                s0 += gelu_f(l0[mt][r] + lb0);
                s1 += gelu_f(l1[mt][r] + lb1);
            }
        }
        s0 += __shfl_xor(s0, 16); s0 += __shfl_xor(s0, 32);
        s1 += __shfl_xor(s1, 16); s1 += __shfl_xor(s1, 32);
        if (quad == 0) {
            int g = bs[0];
            atomicAdd(&local_sum[g * LDIM + c0], s0);
            atomicAdd(&local_sum[g * LDIM + c1], s1);
        }
    } else {
        int cur = -1;
        float s0 = 0.f, s1 = 0.f;
        #pragma unroll
        for (int mt = 0; mt < 4; ++mt) {
            #pragma unroll
            for (int r = 0; r < 4; ++r) {
                int lrow = mt * 16 + quad * 4 + r;
                if (base + lrow < N) {
                    int g = bs[lrow];
                    if (g != cur) {
                        if (cur >= 0) {
                            atomicAdd(&local_sum[cur * LDIM + c0], s0);
                            atomicAdd(&local_sum[cur * LDIM + c1], s1);
                        }
                        cur = g; s0 = 0.f; s1 = 0.f;
                    }
                    s0 += gelu_f(l0[mt][r] + lb0);
                    s1 += gelu_f(l1[mt][r] + lb1);
                }
            }
        }
        if (cur >= 0) {
            atomicAdd(&local_sum[cur * LDIM + c0], s0);
            atomicAdd(&local_sum[cur * LDIM + c1], s1);
        }
    }
}

// ---------------- Kernel 2: per-segment softmax stats ----------------
__device__ __forceinline__ int lower_bound_i(const int* a, int n, int v) {
    int lo = 0, hi = n;
    while (lo < hi) { int mid = (lo + hi) >> 1; if (a[mid] < v) lo = mid + 1; else hi = mid; }
    return lo;
}

__global__ __launch_bounds__(256) void k_stats(
    const int* __restrict__ batch, const float* __restrict__ gate,
    float* __restrict__ aw, float* __restrict__ segdenom,
    int* __restrict__ segstart, int N)
{
    const int g   = blockIdx.x;
    const int tid = threadIdx.x;
    const int wave = tid >> 6;
    const int lane = tid & 63;

    __shared__ int sse[2];
    __shared__ float wred[4];

    if (tid == 0) sse[0] = lower_bound_i(batch, N, g);
    if (tid == 1) sse[1] = lower_bound_i(batch, N, g + 1);
    __syncthreads();
    const int start = sse[0], end = sse[1];
    if (tid == 0) segstart[g] = start;

    float m = -FLT_MAX;
    for (int i = start + tid; i < end; i += 256) m = fmaxf(m, gate[i]);
    #pragma unroll
    for (int off = 32; off > 0; off >>= 1) m = fmaxf(m, __shfl_xor(m, off));
    if (lane == 0) wred[wave] = m;
    __syncthreads();
    m = fmaxf(fmaxf(wred[0], wred[1]), fmaxf(wred[2], wred[3]));
    __syncthreads();

    float s = 0.f;
    for (int i = start + tid; i < end; i += 256) {
        float e = expf(gate[i] - m);
        aw[i] = e;
        s += e;
    }
    #pragma unroll
    for (int off = 32; off > 0; off >>= 1) s += __shfl_xor(s, off);
    if (lane == 0) wred[wave] = s;
    __syncthreads();
    if (tid == 0) segdenom[g] = wred[0] + wred[1] + wred[2] + wred[3];
}

// ---------------- Kernel 3: streaming pooling, 2 blocks per segment ----------------
__global__ __launch_bounds__(256) void k_pool(
    const float* __restrict__ x,
    const float* __restrict__ aw, const float* __restrict__ segdenom,
    const int* __restrict__ segstart, const float* __restrict__ local_sum,
    float* __restrict__ out)
{
    const int g    = blockIdx.x >> 1;
    const int half = blockIdx.x & 1;
    const int tid  = threadIdx.x;
    const int rg   = tid >> 5;          // 0..7 row group
    const int c4   = tid & 31;          // 0..31 float4 within 128-col half

    __shared__ float psum[8][128];
    __shared__ float pmax[8][128];
    __shared__ float patt[8][128];

    const int start = segstart[g];
    const int end   = segstart[g + 1];
    const int cnt   = end - start;

    const float* xb = x + half * 128 + c4 * 4;

    float sx = 0, sy = 0, sz = 0, sw = 0;
    float ax = 0, ay = 0, az = 0, aw4 = 0;
    float mx = -FLT_MAX, my = -FLT_MAX, mz = -FLT_MAX, mw = -FLT_MAX;

    int i = start + rg;
    #define POOL_BODY(ri)                                                    \
        {                                                                    \
            float e = aw[ri];                                                \
            float4 v = *(const float4*)(xb + (long)(ri) * D);                \
            sx += v.x; sy += v.y; sz += v.z; sw += v.w;                      \
            ax += e * v.x; ay += e * v.y; az += e * v.z; aw4 += e * v.w;     \
            mx = fmaxf(mx, v.x); my = fmaxf(my, v.y);                        \
            mz = fmaxf(mz, v.z); mw = fmaxf(mw, v.w);                        \
        }
    for (; i + 8 < end; i += 16) { POOL_BODY(i); POOL_BODY(i + 8); }
    if (i < end) POOL_BODY(i);
    #undef POOL_BODY

    const int cb = c4 * 4;
    psum[rg][cb] = sx; psum[rg][cb+1] = sy; psum[rg][cb+2] = sz; psum[rg][cb+3] = sw;
    patt[rg][cb] = ax; patt[rg][cb+1] = ay; patt[rg][cb+2] = az; patt[rg][cb+3] = aw4;
    pmax[rg][cb] = mx; pmax[rg][cb+1] = my; pmax[rg][cb+2] = mz; pmax[rg][cb+3] = mw;
    __syncthreads();

    const float inv  = 1.0f / fmaxf((float)cnt, 1.0f);
    const float dn   = segdenom[g];
    const float invd = (dn > 0.f) ? 1.0f / dn : 0.f;
    const long  o    = (long)g * 896;

    if (tid < 128) {
        int c = tid;
        float s = 0.f, a = 0.f, mm = -FLT_MAX;
        #pragma unroll
        for (int r = 0; r < 8; ++r) {
            s += psum[r][c];
            a += patt[r][c];
            mm = fmaxf(mm, pmax[r][c]);
        }
        if (cnt == 0) mm = -INFINITY;
        out[o + half * 128 + c]       = s * inv;
        out[o + 256 + half * 128 + c] = mm;
        out[o + 512 + half * 128 + c] = a * invd;
        if (half == 1) out[o + 768 + c] = local_sum[g * LDIM + c] * inv;
    }
}

// ---------------- launch ----------------
extern "C" void kernel_launch(void* const* d_in, const int* in_sizes, int n_in,
                              void* d_out, int out_size, void* d_ws, size_t ws_size,
                              hipStream_t stream) {
    const float* x   = (const float*)d_in[0];
    const int* batch = (const int*)d_in[1];
    const float* w1  = (const float*)d_in[2];
    const float* b1  = (const float*)d_in[3];
    const float* w2  = (const float*)d_in[4];
    const float* b2  = (const float*)d_in[5];
    const float* lpw = (const float*)d_in[6];
    const float* lpb = (const float*)d_in[7];
    float* out = (float*)d_out;

    const int N = in_sizes[0] / D;
    const int G = out_size / 896;

    char* ws = (char*)d_ws;
    size_t off = 0;
    float* gate      = (float*)(ws + off); off += (((size_t)N * 4) + 255) & ~(size_t)255;
    float* aw        = (float*)(ws + off); off += (((size_t)N * 4) + 255) & ~(size_t)255;
    bf16*  w1T       = (bf16*)(ws + off);  off += (size_t)HDIM * D * 2;
    bf16*  lpT       = (bf16*)(ws + off);  off += (size_t)LDIM * D * 2;
    float* local_sum = (float*)(ws + off); off += (size_t)G * LDIM * 4;
    float* segdenom  = (float*)(ws + off); off += (size_t)G * 4;
    int*   segstart  = (int*)(ws + off);   off += (size_t)(G + 1) * 4;

    const int prep_threads = G * LDIM;
    k_prep<<<(prep_threads + 255) / 256, 256, 0, stream>>>(w1, lpw, w1T, lpT, local_sum,
                                                           segstart, G, N);
    k_gate_local<<<(int)((N + 63) / 64), 256, 0, stream>>>(x, batch, w1T, b1, w2, b2,
                                                           lpT, lpb, gate, local_sum, N);
    k_stats<<<G, 256, 0, stream>>>(batch, gate, aw, segdenom, segstart, N);
    k_pool<<<2 * G, 256, 0, stream>>>(x, aw, segdenom, segstart, local_sum, out);
}